// Round 4
// baseline (860.905 us; speedup 1.0000x reference)
//
#include <hip/hip_runtime.h>
#include <hip/hip_cooperative_groups.h>

namespace cg = cooperative_groups;

#define B_ 256
#define N_ 64
#define T_ 4096
#define H_ 16

typedef float f32x4 __attribute__((ext_vector_type(4)));

__device__ __forceinline__ void fma4(float4& a, float w, const float4& v) {
  a.x = fmaf(w, v.x, a.x);
  a.y = fmaf(w, v.y, a.y);
  a.z = fmaf(w, v.z, a.z);
  a.w = fmaf(w, v.w, a.w);
}

// ---------- Cooperative fused kernel ----------
// grid = B*2 blocks of 512 threads; block (b,h) owns t-range [h*2048,(h+1)*2048).
// Phase 1: partial sum/sumsq per row over own half-T (x read once from HBM).
// grid.sync(). Phase 2: energy -> analytic softmax -> matmul, re-reading own
// x tile (L3-hot: at sync, L3 holds last-touched 256 of 268 MB).
__global__ __launch_bounds__(512, 4) void k_coop(const float* __restrict__ x,
                                                 const float* __restrict__ Wq,
                                                 const float* __restrict__ bq,
                                                 const float* __restrict__ Wk,
                                                 const float* __restrict__ bk,
                                                 float* __restrict__ out,
                                                 float* __restrict__ attn,
                                                 float* __restrict__ sp,
                                                 float* __restrict__ ssp) {
  const int b   = blockIdx.x >> 1;
  const int h   = blockIdx.x & 1;
  const int tid = threadIdx.x;
  const int lane = tid & 63;
  const int wid  = tid >> 6;

  // ---- phase 1: 8 rows per wave, 2048 floats per row ----
  const float* __restrict__ xbase = x + (size_t)b * (N_ * T_) + h * 2048;
  for (int r = 0; r < 8; ++r) {
    const int row = (wid << 3) + r;
    const float* __restrict__ xr = xbase + (size_t)row * T_;
    float s = 0.f, ss = 0.f;
#pragma unroll
    for (int k = 0; k < 8; ++k) {
      const float4 v = *(const float4*)(xr + k * 256 + lane * 4);
      s  += v.x + v.y + v.z + v.w;
      ss += v.x * v.x + v.y * v.y + v.z * v.z + v.w * v.w;
    }
#pragma unroll
    for (int off = 32; off > 0; off >>= 1) {
      s  += __shfl_down(s, off, 64);
      ss += __shfl_down(ss, off, 64);
    }
    if (lane == 0) {
      const int idx = ((b * N_ + row) << 1) + h;
      sp[idx]  = s;
      ssp[idx] = ss;
    }
  }
  __threadfence();
  cg::this_grid().sync();

  // ---- phase 2a: energy + analytic softmax (identical math to k_fused) ----
  __shared__ float e[N_];
  __shared__ float wt[N_ * N_];               // wt[j*64+i] = w[i][j] (+1 diag)
  if (tid < N_) {
    const int idx = (b * N_ + tid) << 1;
    const float S  = sp[idx] + sp[idx + 1];
    const float SS = ssp[idx] + ssp[idx + 1];
    const float m  = S * (1.0f / T_);
    e[tid] = SS * (1.0f / T_) - m * m;
  }
  float c1 = 0.f, c3 = 0.f;
#pragma unroll
  for (int hh = 0; hh < H_; ++hh) { c1 += Wq[hh] * Wk[hh]; c3 += bq[hh] * Wk[hh]; }
  __syncthreads();

  const int i  = (wid << 3) + (lane >> 3);
  const int jg = lane & 7;
  const float beta = 0.25f * (c1 * e[i] + c3);   // scale = H^-0.5 = 0.25
  float l[8];
  float mx = -3.0e38f;
#pragma unroll
  for (int c = 0; c < 8; ++c) {
    const int j = (jg << 3) + c;
    const float lj = (j == i) ? -3.0e38f : beta * e[j];
    l[c] = lj;
    mx = fmaxf(mx, lj);
  }
#pragma unroll
  for (int off = 1; off < 8; off <<= 1) mx = fmaxf(mx, __shfl_xor(mx, off, 64));
  float sum = 0.f;
#pragma unroll
  for (int c = 0; c < 8; ++c) {
    const int j = (jg << 3) + c;
    const float ex = (j == i) ? 0.f : __expf(l[c] - mx);
    l[c] = ex;
    sum += ex;
  }
#pragma unroll
  for (int off = 1; off < 8; off <<= 1) sum += __shfl_xor(sum, off, 64);
  const float inv = 1.0f / sum;
#pragma unroll
  for (int c = 0; c < 8; ++c) {
    const int j = (jg << 3) + c;
    const float w = l[c] * inv;
    l[c] = w;
    wt[j * N_ + i] = w + ((j == i) ? 1.0f : 0.f);  // residual folded in
  }
  if (h == 0) {                               // one block per b emits attn
    float* __restrict__ ar = attn + (size_t)b * (N_ * N_) + i * N_ + (jg << 3);
#pragma unroll
    for (int c = 0; c < 8; ++c) ar[c] = l[c];
  }
  __syncthreads();

  // ---- phase 2b: matmul. 4-wave groups share a 256-wide chunk; wave owns
  // 16 i-rows (acc = 64 VGPR). Group g covers chunks tc = g*4..g*4+3.
  const int ig    = wid & 3;                  // wave within group
  const int grp   = wid >> 2;                 // 0..1
  const int ibase = ig << 4;                  // 16 i-rows
  for (int tc = 0; tc < 4; ++tc) {
    const int tt = h * 8 + grp * 4 + tc;      // global 256-chunk index
    const float* __restrict__ xb =
        x + (size_t)b * (N_ * T_) + tt * 256 + lane * 4;
    float4 acc[16];
#pragma unroll
    for (int ii = 0; ii < 16; ++ii) acc[ii] = make_float4(0.f, 0.f, 0.f, 0.f);
#pragma unroll 4
    for (int j = 0; j < N_; ++j) {
      const float4 xv = *(const float4*)(xb + (size_t)j * T_);
      const float4 w0 = *(const float4*)(&wt[j * N_ + ibase]);
      const float4 w1 = *(const float4*)(&wt[j * N_ + ibase + 4]);
      const float4 w2 = *(const float4*)(&wt[j * N_ + ibase + 8]);
      const float4 w3 = *(const float4*)(&wt[j * N_ + ibase + 12]);
      fma4(acc[0],  w0.x, xv); fma4(acc[1],  w0.y, xv);
      fma4(acc[2],  w0.z, xv); fma4(acc[3],  w0.w, xv);
      fma4(acc[4],  w1.x, xv); fma4(acc[5],  w1.y, xv);
      fma4(acc[6],  w1.z, xv); fma4(acc[7],  w1.w, xv);
      fma4(acc[8],  w2.x, xv); fma4(acc[9],  w2.y, xv);
      fma4(acc[10], w2.z, xv); fma4(acc[11], w2.w, xv);
      fma4(acc[12], w3.x, xv); fma4(acc[13], w3.y, xv);
      fma4(acc[14], w3.z, xv); fma4(acc[15], w3.w, xv);
    }
    float* __restrict__ ob =
        out + (size_t)b * (N_ * T_) + tt * 256 + lane * 4;
#pragma unroll
    for (int ii = 0; ii < 16; ++ii) {
      __builtin_nontemporal_store(*(const f32x4*)&acc[ii],
          (f32x4*)(ob + (size_t)(ibase + ii) * T_));
    }
  }
}

// ================= fallback path (verified round-3 code) =================

__global__ __launch_bounds__(256) void k_var(const float* __restrict__ x,
                                             float* __restrict__ energy) {
  const int wid  = threadIdx.x >> 6;
  const int lane = threadIdx.x & 63;
  const int row  = blockIdx.x * 4 + wid;           // b*N + n
  const float* __restrict__ xr = x + (size_t)row * T_;
  float s = 0.f, ss = 0.f;
#pragma unroll
  for (int k = 0; k < 16; ++k) {
    const float4 v = *(const float4*)(xr + (k * 64 + lane) * 4);
    s  += v.x + v.y + v.z + v.w;
    ss += v.x * v.x + v.y * v.y + v.z * v.z + v.w * v.w;
  }
#pragma unroll
  for (int off = 32; off > 0; off >>= 1) {
    s  += __shfl_down(s, off, 64);
    ss += __shfl_down(ss, off, 64);
  }
  if (lane == 0) {
    const float m = s * (1.0f / T_);
    energy[row] = ss * (1.0f / T_) - m * m;
  }
}

__global__ __launch_bounds__(64) void k_attn(const float* __restrict__ energy,
                                             const float* __restrict__ Wq,
                                             const float* __restrict__ bq,
                                             const float* __restrict__ Wk,
                                             const float* __restrict__ bk,
                                             float* __restrict__ attn) {
  const int b = blockIdx.x;
  const int i = threadIdx.x;
  __shared__ float e[N_];
  __shared__ float wrow[N_][N_ + 1];
  e[i] = energy[b * N_ + i];
  float c1 = 0.f, c3 = 0.f;
#pragma unroll
  for (int h = 0; h < H_; ++h) { c1 += Wq[h] * Wk[h]; c3 += bq[h] * Wk[h]; }
  __syncthreads();
  const float beta = 0.25f * (c1 * e[i] + c3);
  float l[N_];
  float mx = -3.0e38f;
#pragma unroll
  for (int j = 0; j < N_; ++j) {
    float lj = beta * e[j];
    if (j == i) lj = -3.0e38f;
    l[j] = lj;
    mx = fmaxf(mx, lj);
  }
  float sum = 0.f;
#pragma unroll
  for (int j = 0; j < N_; ++j) {
    float ex = (j == i) ? 0.f : __expf(l[j] - mx);
    l[j] = ex;
    sum += ex;
  }
  const float inv = 1.0f / sum;
#pragma unroll
  for (int j = 0; j < N_; ++j) wrow[i][j] = l[j] * inv;
  __syncthreads();
  float* __restrict__ ab = attn + (size_t)b * (N_ * N_);
#pragma unroll
  for (int r = 0; r < N_; ++r) ab[r * N_ + i] = wrow[r][i];
}

__device__ __forceinline__ void out_mainloop(const float* __restrict__ x,
                                             float* __restrict__ out,
                                             const float* __restrict__ wt,
                                             int b, int tt, int tid) {
  const int lane = tid & 63;
  const int wid  = tid >> 6;
  const int ibase = wid << 3;
  const float* __restrict__ xb =
      x + (size_t)b * (N_ * T_) + tt * 256 + lane * 4;
  float4 acc[8];
#pragma unroll
  for (int ii = 0; ii < 8; ++ii) acc[ii] = make_float4(0.f, 0.f, 0.f, 0.f);
#pragma unroll 4
  for (int j = 0; j < N_; ++j) {
    const float4 xv = *(const float4*)(xb + (size_t)j * T_);
    const float4 wa = *(const float4*)(&wt[j * N_ + ibase]);
    const float4 wb = *(const float4*)(&wt[j * N_ + ibase + 4]);
    fma4(acc[0], wa.x, xv); fma4(acc[1], wa.y, xv);
    fma4(acc[2], wa.z, xv); fma4(acc[3], wa.w, xv);
    fma4(acc[4], wb.x, xv); fma4(acc[5], wb.y, xv);
    fma4(acc[6], wb.z, xv); fma4(acc[7], wb.w, xv);
  }
  float* __restrict__ ob =
      out + (size_t)b * (N_ * T_) + tt * 256 + lane * 4;
#pragma unroll
  for (int ii = 0; ii < 8; ++ii) {
    __builtin_nontemporal_store(*(const f32x4*)&acc[ii],
        (f32x4*)(ob + (size_t)(ibase + ii) * T_));
  }
}

__global__ __launch_bounds__(512, 4) void k_fused(const float* __restrict__ x,
                                                  const float* __restrict__ energy,
                                                  const float* __restrict__ Wq,
                                                  const float* __restrict__ bq,
                                                  const float* __restrict__ Wk,
                                                  const float* __restrict__ bk,
                                                  float* __restrict__ out,
                                                  float* __restrict__ attn) {
  const int b  = blockIdx.x >> 4;
  const int tt = blockIdx.x & 15;
  const int tid  = threadIdx.x;
  const int lane = tid & 63;
  const int wid  = tid >> 6;
  __shared__ float e[N_];
  __shared__ float wt[N_ * N_];
  if (tid < N_) e[tid] = energy[b * N_ + tid];
  float c1 = 0.f, c3 = 0.f;
#pragma unroll
  for (int h = 0; h < H_; ++h) { c1 += Wq[h] * Wk[h]; c3 += bq[h] * Wk[h]; }
  __syncthreads();
  const int i  = (wid << 3) + (lane >> 3);
  const int jg = lane & 7;
  const float beta = 0.25f * (c1 * e[i] + c3);
  float l[8];
  float mx = -3.0e38f;
#pragma unroll
  for (int c = 0; c < 8; ++c) {
    const int j = (jg << 3) + c;
    const float lj = (j == i) ? -3.0e38f : beta * e[j];
    l[c] = lj;
    mx = fmaxf(mx, lj);
  }
#pragma unroll
  for (int off = 1; off < 8; off <<= 1) mx = fmaxf(mx, __shfl_xor(mx, off, 64));
  float sum = 0.f;
#pragma unroll
  for (int c = 0; c < 8; ++c) {
    const int j = (jg << 3) + c;
    const float ex = (j == i) ? 0.f : __expf(l[c] - mx);
    l[c] = ex;
    sum += ex;
  }
#pragma unroll
  for (int off = 1; off < 8; off <<= 1) sum += __shfl_xor(sum, off, 64);
  const float inv = 1.0f / sum;
#pragma unroll
  for (int c = 0; c < 8; ++c) {
    const int j = (jg << 3) + c;
    const float w = l[c] * inv;
    l[c] = w;
    wt[j * N_ + i] = w + ((j == i) ? 1.0f : 0.f);
  }
  if (tt == 0) {
    float* __restrict__ ar = attn + (size_t)b * (N_ * N_) + i * N_ + (jg << 3);
#pragma unroll
    for (int c = 0; c < 8; ++c) ar[c] = l[c];
  }
  __syncthreads();
  out_mainloop(x, out, wt, b, tt, tid);
}

__global__ __launch_bounds__(512, 4) void k_out2(const float* __restrict__ x,
                                                 const float* __restrict__ attn,
                                                 float* __restrict__ out) {
  const int b  = blockIdx.x >> 4;
  const int tt = blockIdx.x & 15;
  const int tid = threadIdx.x;
  __shared__ float wt[N_ * N_];
  const float* __restrict__ ab = attn + (size_t)b * (N_ * N_);
#pragma unroll
  for (int k = 0; k < 2; ++k) {
    const int idx = k * 512 + tid;
    const int i  = idx & 63;
    const int jq = idx >> 6;
    float4 v = *(const float4*)(ab + i * N_ + jq * 4);
    const int dj = i - jq * 4;
    if      (dj == 0) v.x += 1.0f;
    else if (dj == 1) v.y += 1.0f;
    else if (dj == 2) v.z += 1.0f;
    else if (dj == 3) v.w += 1.0f;
    wt[(jq * 4 + 0) * N_ + i] = v.x;
    wt[(jq * 4 + 1) * N_ + i] = v.y;
    wt[(jq * 4 + 2) * N_ + i] = v.z;
    wt[(jq * 4 + 3) * N_ + i] = v.w;
  }
  __syncthreads();
  out_mainloop(x, out, wt, b, tt, tid);
}

extern "C" void kernel_launch(void* const* d_in, const int* in_sizes, int n_in,
                              void* d_out, int out_size, void* d_ws, size_t ws_size,
                              hipStream_t stream) {
  const float* x  = (const float*)d_in[0];
  const float* Wq = (const float*)d_in[1];
  const float* bq = (const float*)d_in[2];
  const float* Wk = (const float*)d_in[3];
  const float* bk = (const float*)d_in[4];
  float* out  = (float*)d_out;
  float* attn = out + (size_t)B_ * N_ * T_;

  // Primary: cooperative fused kernel. Needs sp+ssp = B*N*2*2 floats (256 KB).
  const size_t need_coop = (size_t)B_ * N_ * 4 * sizeof(float);
  if (d_ws != nullptr && ws_size >= need_coop) {
    float* sp  = (float*)d_ws;
    float* ssp = sp + (size_t)B_ * N_ * 2;
    void* args[9] = {(void*)&x, (void*)&Wq, (void*)&bq, (void*)&Wk, (void*)&bk,
                     (void*)&out, (void*)&attn, (void*)&sp, (void*)&ssp};
    const hipError_t err = hipLaunchCooperativeKernel(
        (const void*)k_coop, dim3(B_ * 2), dim3(512), args, 0, stream);
    if (err == hipSuccess) return;
  }
  if (d_ws != nullptr && ws_size >= (size_t)B_ * N_ * sizeof(float)) {
    float* energy = (float*)d_ws;
    hipLaunchKernelGGL(k_var, dim3(B_ * N_ / 4), dim3(256), 0, stream, x, energy);
    hipLaunchKernelGGL(k_fused, dim3(B_ * 16), dim3(512), 0, stream,
                       x, energy, Wq, bq, Wk, bk, out, attn);
  } else {
    float* energy = out;
    hipLaunchKernelGGL(k_var, dim3(B_ * N_ / 4), dim3(256), 0, stream, x, energy);
    hipLaunchKernelGGL(k_attn, dim3(B_), dim3(64), 0, stream,
                       energy, Wq, bq, Wk, bk, attn);
    hipLaunchKernelGGL(k_out2, dim3(B_ * 16), dim3(512), 0, stream, x, attn, out);
  }
}